// Round 1
// baseline (247.548 us; speedup 1.0000x reference)
//
#include <hip/hip_runtime.h>

// Problem constants (from reference)
#define BB 16
#define HH 299
#define WW 299
#define KK 8
#define HWPIX (HH * WW)        // 89401
#define NPIX (BB * HWPIX)      // 1430416

__global__ __launch_bounds__(256) void gauss_net_kernel(
    const float4* __restrict__ spatial,  // (N_POINTS, 4) as float4
    const float*  __restrict__ wi,       // (B, 2, H, W, K)
    const float4* __restrict__ ori,      // (B, H, W, 4) as float4
    float* __restrict__ out)             // concatenated outputs
{
    int p = blockIdx.x * blockDim.x + threadIdx.x;
    if (p >= NPIX) return;

    int b   = p / HWPIX;
    int rem = p - b * HWPIX;

    // weights: [b][0][h][w][0..7], indices: [b][1][h][w][0..7] — each 32B contiguous
    const float4* wvec = (const float4*)(wi + ((size_t)(2 * b) * HWPIX + rem) * KK);
    const float4* ivec = (const float4*)(wi + ((size_t)(2 * b + 1) * HWPIX + rem) * KK);
    float4 w0 = wvec[0], w1 = wvec[1];
    float4 i0 = ivec[0], i1 = ivec[1];

    int id[KK] = { (int)i0.x, (int)i0.y, (int)i0.z, (int)i0.w,
                   (int)i1.x, (int)i1.y, (int)i1.z, (int)i1.w };
    float wt[KK] = { w0.x, w0.y, w0.z, w0.w, w1.x, w1.y, w1.z, w1.w };

    float ax = 0.f, ay = 0.f, az = 0.f, aw = 0.f;
#pragma unroll
    for (int k = 0; k < KK; ++k) {
        float4 g = spatial[id[k]];
        float  c = wt[k];
        ax = fmaf(g.x, c, ax);
        ay = fmaf(g.y, c, ay);
        az = fmaf(g.z, c, az);
        aw = fmaf(g.w, c, aw);
    }

    float4 o = ori[p];

    float alpha = aw * (1.0f / 255.0f);
    float r = fmaf(ax, alpha, o.x);
    float g = fmaf(ay, alpha, o.y);
    float bl = fmaf(az, alpha, o.z);
    bool  oa_pos = (o.w > 0.0f);
    if (!oa_pos) { r = 0.f; g = 0.f; bl = 0.f; }

    // x_rgba = clip(concat(x_rgb, ori_alpha), 0, 255)
    float cr = fminf(fmaxf(r, 0.f), 255.f);
    float cg = fminf(fmaxf(g, 0.f), 255.f);
    float cb = fminf(fmaxf(bl, 0.f), 255.f);
    float ca = fminf(fmaxf(o.w, 0.f), 255.f);

    // Output layout (flat float offsets):
    //   x       : [0,            NPIX*4)
    //   x_rgba  : [NPIX*4,       NPIX*8)
    //   cla     : [NPIX*8,       NPIX*8 + BB*3*HWPIX)
    //   ori_img : [... ,         + NPIX*4)
    //   ori_cla : [... ,         + BB*3*HWPIX)
    float4* out_x    = (float4*)out;
    float4* out_rgba = out_x + NPIX;
    float*  out_cla  = (float*)(out_rgba + NPIX);
    float4* out_ori  = (float4*)(out_cla + (size_t)BB * 3 * HWPIX);
    float*  out_ocla = (float*)(out_ori + NPIX);

    out_x[p]    = make_float4(ax, ay, az, aw);
    out_rgba[p] = make_float4(cr, cg, cb, ca);
    out_ori[p]  = o;

    size_t cbase = (size_t)b * 3 * HWPIX + rem;
    bool ca_pos = (ca > 0.0f);
    out_cla[cbase]             = ca_pos ? cr : 255.0f;
    out_cla[cbase + HWPIX]     = ca_pos ? cg : 255.0f;
    out_cla[cbase + 2 * HWPIX] = ca_pos ? cb : 255.0f;

    out_ocla[cbase]             = oa_pos ? o.x : 255.0f;
    out_ocla[cbase + HWPIX]     = oa_pos ? o.y : 255.0f;
    out_ocla[cbase + 2 * HWPIX] = oa_pos ? o.z : 255.0f;
}

extern "C" void kernel_launch(void* const* d_in, const int* in_sizes, int n_in,
                              void* d_out, int out_size, void* d_ws, size_t ws_size,
                              hipStream_t stream) {
    const float4* spatial = (const float4*)d_in[0];  // (200000, 4)
    const float*  wi      = (const float*)d_in[1];   // (16, 2, 299, 299, 8)
    const float4* ori     = (const float4*)d_in[2];  // (16, 299, 299, 4)
    float* out = (float*)d_out;

    int threads = 256;
    int blocks = (NPIX + threads - 1) / threads;
    gauss_net_kernel<<<blocks, threads, 0, stream>>>(spatial, wi, ori, out);
}

// Round 2
// 233.875 us; speedup vs baseline: 1.0585x; 1.0585x over previous
//
#include <hip/hip_runtime.h>

// Problem constants (from reference)
#define BB 16
#define HH 299
#define WW 299
#define KK 8
#define HWPIX (HH * WW)        // 89401
#define NPIX (BB * HWPIX)      // 1430416
#define PPT 2                  // pixels per thread (MLP: 16 gathers in flight)
#define TPB 256
#define SPAN (TPB * PPT)

typedef float f4 __attribute__((ext_vector_type(4)));

__global__ __launch_bounds__(TPB) void gauss_net_kernel(
    const f4* __restrict__ spatial,  // (N_POINTS, 4)
    const f4* __restrict__ wi4,      // (B, 2, H, W, K) viewed as f4
    const f4* __restrict__ ori,      // (B, H, W, 4)
    float* __restrict__ out)
{
    const int tbase = blockIdx.x * SPAN + threadIdx.x;

    // Output layout (flat float offsets)
    f4*    out_x    = (f4*)out;
    f4*    out_rgba = out_x + NPIX;
    float* out_cla  = (float*)(out_rgba + NPIX);
    f4*    out_ori  = (f4*)(out_cla + (size_t)BB * 3 * HWPIX);
    float* out_ocla = (float*)(out_ori + NPIX);

    int  p[PPT], bidx[PPT], rem[PPT];
    bool act[PPT];
    f4   w0[PPT], w1[PPT], i0[PPT], i1[PPT], o[PPT];

    // Phase 1: issue ALL streaming loads (weights, indices, ori) — nt, read-once
#pragma unroll
    for (int u = 0; u < PPT; ++u) {
        p[u]   = tbase + u * TPB;
        act[u] = (p[u] < NPIX);
        int pc = act[u] ? p[u] : 0;
        bidx[u] = pc / HWPIX;
        rem[u]  = pc - bidx[u] * HWPIX;
        size_t wb = ((size_t)(2 * bidx[u]) * HWPIX + rem[u]) * 2;  // f4 units
        size_t ib = wb + (size_t)HWPIX * 2;
        w0[u] = __builtin_nontemporal_load(wi4 + wb);
        w1[u] = __builtin_nontemporal_load(wi4 + wb + 1);
        i0[u] = __builtin_nontemporal_load(wi4 + ib);
        i1[u] = __builtin_nontemporal_load(wi4 + ib + 1);
        o[u]  = __builtin_nontemporal_load(ori + pc);
    }

    // Phase 2: issue ALL gathers (random 16B; table is L2-resident) before
    // consuming any — maximize outstanding misses per wave.
    f4 g[PPT][KK];
#pragma unroll
    for (int u = 0; u < PPT; ++u) {
        int id[KK] = { (int)i0[u].x, (int)i0[u].y, (int)i0[u].z, (int)i0[u].w,
                       (int)i1[u].x, (int)i1[u].y, (int)i1[u].z, (int)i1[u].w };
#pragma unroll
        for (int k = 0; k < KK; ++k) g[u][k] = spatial[id[k]];
    }

    // Phase 3: reduce + epilogue + nt stores
#pragma unroll
    for (int u = 0; u < PPT; ++u) {
        if (!act[u]) continue;
        float wt[KK] = { w0[u].x, w0[u].y, w0[u].z, w0[u].w,
                         w1[u].x, w1[u].y, w1[u].z, w1[u].w };
        f4 acc = (f4){0.f, 0.f, 0.f, 0.f};
#pragma unroll
        for (int k = 0; k < KK; ++k) acc += g[u][k] * wt[k];

        f4 ov = o[u];
        float alpha = acc.w * (1.0f / 255.0f);
        float r  = fmaf(acc.x, alpha, ov.x);
        float gr = fmaf(acc.y, alpha, ov.y);
        float bl = fmaf(acc.z, alpha, ov.z);
        bool oa_pos = (ov.w > 0.0f);
        if (!oa_pos) { r = 0.f; gr = 0.f; bl = 0.f; }

        float cr = fminf(fmaxf(r,  0.f), 255.f);
        float cg = fminf(fmaxf(gr, 0.f), 255.f);
        float cb = fminf(fmaxf(bl, 0.f), 255.f);
        float ca = fminf(fmaxf(ov.w, 0.f), 255.f);

        __builtin_nontemporal_store(acc, out_x + p[u]);
        __builtin_nontemporal_store((f4){cr, cg, cb, ca}, out_rgba + p[u]);
        __builtin_nontemporal_store(ov, out_ori + p[u]);

        size_t cbase = (size_t)bidx[u] * 3 * HWPIX + rem[u];
        bool ca_pos = (ca > 0.0f);
        __builtin_nontemporal_store(ca_pos ? cr : 255.0f, out_cla + cbase);
        __builtin_nontemporal_store(ca_pos ? cg : 255.0f, out_cla + cbase + HWPIX);
        __builtin_nontemporal_store(ca_pos ? cb : 255.0f, out_cla + cbase + 2 * HWPIX);

        __builtin_nontemporal_store(oa_pos ? ov.x : 255.0f, out_ocla + cbase);
        __builtin_nontemporal_store(oa_pos ? ov.y : 255.0f, out_ocla + cbase + HWPIX);
        __builtin_nontemporal_store(oa_pos ? ov.z : 255.0f, out_ocla + cbase + 2 * HWPIX);
    }
}

extern "C" void kernel_launch(void* const* d_in, const int* in_sizes, int n_in,
                              void* d_out, int out_size, void* d_ws, size_t ws_size,
                              hipStream_t stream) {
    const f4* spatial = (const f4*)d_in[0];
    const f4* wi4     = (const f4*)d_in[1];
    const f4* ori     = (const f4*)d_in[2];
    float* out = (float*)d_out;

    int blocks = (NPIX + SPAN - 1) / SPAN;
    gauss_net_kernel<<<blocks, TPB, 0, stream>>>(spatial, wi4, ori, out);
}